// Round 4
// baseline (2498.300 us; speedup 1.0000x reference)
//
#include <hip/hip_runtime.h>
#include <hip/hip_bf16.h>
#include <cstdint>
#include <cstddef>

// Problem constants
#define NROWS 8192
#define DIM   2048
#define HIDN  1024
#define QKV3  3072
#define EPSV  1e-5f

typedef __attribute__((ext_vector_type(8))) short bf16x8;
typedef __attribute__((ext_vector_type(4))) float f32x4;

__device__ __forceinline__ unsigned short f2bf(float x) {
    __hip_bfloat16 h = __float2bfloat16(x);
    return *reinterpret_cast<unsigned short*>(&h);
}
__device__ __forceinline__ float bf2f(unsigned short u) {
    return __uint_as_float((unsigned)u << 16);
}

__device__ __forceinline__ void gload_lds16(const void* g, void* l) {
    __builtin_amdgcn_global_load_lds(
        (const __attribute__((address_space(1))) void*)g,
        (__attribute__((address_space(3))) void*)l, 16, 0, 0);
}

template <int N> __device__ __forceinline__ void vmwait() {
    if constexpr (N == 8)      asm volatile("s_waitcnt vmcnt(8)" ::: "memory");
    else if constexpr (N == 6) asm volatile("s_waitcnt vmcnt(6)" ::: "memory");
    else if constexpr (N == 2) asm volatile("s_waitcnt vmcnt(2)" ::: "memory");
    else if constexpr (N == 0) asm volatile("s_waitcnt vmcnt(0)" ::: "memory");
}
__device__ __forceinline__ void barrier_mem() {
    asm volatile("s_barrier" ::: "memory");
}

// ---------------- f32 -> bf16 elementwise convert, two tensors -----------------
__global__ __launch_bounds__(256) void cvt2_f32_bf16(const float* __restrict__ inA,
                                                     unsigned short* __restrict__ outA,
                                                     const float* __restrict__ inB,
                                                     unsigned short* __restrict__ outB,
                                                     long n) {
    const int which = blockIdx.x >> 13;           // 8192 blocks per tensor
    const long bid = blockIdx.x & 8191;
    const float* in = which ? inB : inA;
    unsigned short* out = which ? outB : outA;
    long base = (bid * 256 + threadIdx.x) * 8;
    if (base >= n) return;
    float4 a = *(const float4*)(in + base);
    float4 b = *(const float4*)(in + base + 4);
    uint4 r;
    r.x = (unsigned)f2bf(a.x) | ((unsigned)f2bf(a.y) << 16);
    r.y = (unsigned)f2bf(a.z) | ((unsigned)f2bf(a.w) << 16);
    r.z = (unsigned)f2bf(b.x) | ((unsigned)f2bf(b.y) << 16);
    r.w = (unsigned)f2bf(b.z) | ((unsigned)f2bf(b.w) << 16);
    *(uint4*)(out + base) = r;
}

// ---------------- f32 [R][C] -> bf16 [C][R] transpose+convert ------------------
__global__ __launch_bounds__(256) void cvt_transpose(const float* __restrict__ in,
                                                     unsigned short* __restrict__ out,
                                                     int R, int C) {
    __shared__ float tile[32][33];
    const int tx = threadIdx.x, ty = threadIdx.y;   // block (32,8)
    const int c0 = blockIdx.x * 32, r0 = blockIdx.y * 32;
#pragma unroll
    for (int i = 0; i < 4; ++i)
        tile[ty + i * 8][tx] = in[(size_t)(r0 + ty + i * 8) * C + c0 + tx];
    __syncthreads();
#pragma unroll
    for (int i = 0; i < 4; ++i)
        out[(size_t)(c0 + ty + i * 8) * R + r0 + tx] = f2bf(tile[tx][ty + i * 8]);
}

// ============== 256x256 8-phase bf16 GEMM, fragment read-ahead =================
// 512 thr = 8 waves (2M x 4N interleaved), BK=64, LDS 128 KiB double-buffered,
// T2 XOR swizzle. During tile t: MFMA from frag set X (read during t-1), while
// ds_reading tile t+1's frags into set Y and staging tile t+2's halves.
// Stage order per tile: ph1 Ah0(t+2) | ph2 Bh0(t+2) | ph3 Bh1(t+2) | ph4 Ah1(t+2).
// Waits: ph1 vmcnt(8) [A(t+1)h0 landed], ph2 vmcnt(6) [B(t+1)h0+h1],
// ph3 vmcnt(6) [A(t+1)h1], ph4 none. All drain 3-4-phase-old stages.

// stage one half-tile: 2 x gload_lds16 from precomputed per-thread offsets
#define STG(Gp, o0c, o1c, ARR, BUF, HALF, KTS)                                 \
    gload_lds16((Gp) + (o0c) + (KTS), (char*)&ARR[BUF][(HALF) * 8192] + dO0);  \
    gload_lds16((Gp) + (o1c) + (KTS), (char*)&ARR[BUF][(HALF) * 8192] + dO1);

#define RDA(DST, BUF, MB)                                                      \
    _Pragma("unroll") for (int m_ = 0; m_ < 4; ++m_) {                         \
        const char* p_ = (const char*)&sA[BUF][0] + rowA + ((MB) + m_) * 4096; \
        DST[(MB) + m_][0] = *(const bf16x8*)(p_ + o0);                         \
        DST[(MB) + m_][1] = *(const bf16x8*)(p_ + (o0 ^ 64));                  \
    }
#define RDB(DST, BUF)                                                          \
    _Pragma("unroll") for (int n_ = 0; n_ < 4; ++n_) {                         \
        const char* p_ = (const char*)&sB[BUF][0] + rowB + n_ * 8192;          \
        DST[n_][0] = *(const bf16x8*)(p_ + o0);                                \
        DST[n_][1] = *(const bf16x8*)(p_ + (o0 ^ 64));                         \
    }

// kk OUTERMOST: 8 independent MFMAs between dependent accumulate pairs
#define QUADF(AR, BR, mq, nq)                                                  \
    __builtin_amdgcn_s_setprio(1);                                             \
    _Pragma("unroll") for (int kk_ = 0; kk_ < 2; ++kk_)                        \
    _Pragma("unroll") for (int n_ = 0; n_ < 2; ++n_)                           \
    _Pragma("unroll") for (int m_ = 0; m_ < 4; ++m_)                           \
        acc[(mq) + m_][(nq) + n_] = __builtin_amdgcn_mfma_f32_16x16x32_bf16(   \
            AR[(mq) + m_][kk_], BR[(nq) + n_][kk_], acc[(mq) + m_][(nq) + n_], \
            0, 0, 0);                                                          \
    __builtin_amdgcn_s_setprio(0);

// MODE 0: steady; MODE 1: tile T-2 (no stage, waits 6/2/0); MODE 2: tile T-1.
#define KT(BUF, AX, BX, AY, BY, MODE, KTS)                                     \
    /* ph1 */                                                                  \
    if constexpr ((MODE) == 0) { STG(A, gA0c0, gA0c1, sA, BUF, 0, KTS) }       \
    if constexpr ((MODE) == 0) vmwait<8>();                                    \
    if constexpr ((MODE) == 1) vmwait<6>();                                    \
    if constexpr ((MODE) <= 1) { RDA(AY, (BUF) ^ 1, 0) }                       \
    barrier_mem();                                                             \
    QUADF(AX, BX, 0, 0);                                                       \
    barrier_mem();                                                             \
    /* ph2 */                                                                  \
    if constexpr ((MODE) == 0) { STG(Bt, gB0c0, gB0c1, sB, BUF, 0, KTS) }      \
    if constexpr ((MODE) == 0) vmwait<6>();                                    \
    if constexpr ((MODE) == 1) vmwait<2>();                                    \
    if constexpr ((MODE) <= 1) { RDB(BY, (BUF) ^ 1) }                          \
    barrier_mem();                                                             \
    QUADF(AX, BX, 0, 2);                                                       \
    barrier_mem();                                                             \
    /* ph3 */                                                                  \
    if constexpr ((MODE) == 0) { STG(Bt, gB1c0, gB1c1, sB, BUF, 1, KTS) }      \
    if constexpr ((MODE) == 0) vmwait<6>();                                    \
    if constexpr ((MODE) == 1) vmwait<0>();                                    \
    if constexpr ((MODE) <= 1) { RDA(AY, (BUF) ^ 1, 4) }                       \
    barrier_mem();                                                             \
    QUADF(AX, BX, 4, 0);                                                       \
    barrier_mem();                                                             \
    /* ph4 */                                                                  \
    if constexpr ((MODE) == 0) { STG(A, gA1c0, gA1c1, sA, BUF, 1, KTS) }       \
    barrier_mem();                                                             \
    QUADF(AX, BX, 4, 2);                                                       \
    barrier_mem();

template <int EPI>
__global__ __launch_bounds__(512, 2) void gemm256(
    const unsigned short* __restrict__ A0, const unsigned short* __restrict__ B0t,
    const float* __restrict__ bias0, const float* __restrict__ res0, void* __restrict__ C0,
    const unsigned short* __restrict__ A1, const unsigned short* __restrict__ B1t,
    const float* __restrict__ bias1, const float* __restrict__ res1, void* __restrict__ C1,
    int M, int N, int K, int nbx) {
    __shared__ __align__(16) short sA[2][16384];
    __shared__ __align__(16) short sB[2][16384];

    const int tid = threadIdx.x;
    // bijective XCD swizzle (gridDim.x % 8 == 0 for all our launches)
    const int nwg = gridDim.x;
    const int ob = blockIdx.x;
    const int swz = (ob & 7) * (nwg >> 3) + (ob >> 3);
    const int per = nbx * (M >> 8);
    const int which = swz >= per ? 1 : 0;
    const int rem = swz - which * per;
    const int by = rem / nbx, bx = rem % nbx;
    const int tm = by << 8, tn = bx << 8;

    const unsigned short* __restrict__ A  = which ? A1 : A0;
    const unsigned short* __restrict__ Bt = which ? B1t : B0t;
    const float* __restrict__ bias  = which ? bias1 : bias0;
    const float* __restrict__ resid = which ? res1 : res0;

    const int w = tid >> 6, l = tid & 63;
    const int wm = w >> 2, wn = w & 3;           // 2 x 4 waves
    const int lg = l >> 4, lr = l & 15;
    const int o0 = (lg ^ (lr & 7)) << 4;         // swizzled k-slot byte offset
    const int rowA = (16 * wm + lr) << 7;        // byte offset of lane's A row
    const int rowB = (16 * wn + lr) << 7;

    // hoisted per-thread staging constants (element offsets; +KTS per call)
    const int rr0 = tid >> 3;
    const int jj0 = ((tid & 7) ^ (rr0 & 7)) * 8;
    const int cc1 = 512 + tid, rr1 = cc1 >> 3;
    const int jj1 = ((cc1 & 7) ^ (rr1 & 7)) * 8;
    const int gA0c0 = (tm + rr0) * K + jj0;
    const int gA0c1 = (tm + rr1) * K + jj1;
    const int gA1c0 = (tm + 128 + rr0) * K + jj0;
    const int gA1c1 = (tm + 128 + rr1) * K + jj1;
    const int gB0c0 = (tn + rr0) * K + jj0;
    const int gB0c1 = (tn + rr1) * K + jj1;
    const int gB1c0 = (tn + 128 + rr0) * K + jj0;
    const int gB1c1 = (tn + 128 + rr1) * K + jj1;
    const int dO0 = (tid & 0x1C0) * 16;
    const int dO1 = (512 + (tid & 0x1C0)) * 16;

    f32x4 acc[8][4] = {};
    bf16x8 a0f[8][2], b0f[4][2], a1f[8][2], b1f[4][2];

    const int T = K >> 6;                        // K-tiles (even, >= 4)

    // prologue: stage tiles 0 and 1 fully (per-tile order Ah0,Bh0,Bh1,Ah1)
    STG(A,  gA0c0, gA0c1, sA, 0, 0, 0)
    STG(Bt, gB0c0, gB0c1, sB, 0, 0, 0)
    STG(Bt, gB1c0, gB1c1, sB, 0, 1, 0)
    STG(A,  gA1c0, gA1c1, sA, 0, 1, 0)
    STG(A,  gA0c0, gA0c1, sA, 1, 0, 64)
    STG(Bt, gB0c0, gB0c1, sB, 1, 0, 64)
    STG(Bt, gB1c0, gB1c1, sB, 1, 1, 64)
    STG(A,  gA1c0, gA1c1, sA, 1, 1, 64)
    vmwait<8>();                                 // tile 0's 8 loads landed
    barrier_mem();
    RDA(a0f, 0, 0)
    RDB(b0f, 0)
    RDA(a0f, 0, 4)
    asm volatile("s_waitcnt lgkmcnt(0)" ::: "memory");  // reads done before
    barrier_mem();                                      // tile0 ph1 stages sA[0]

    int kt = 0;
    for (int tt = 0; tt + 4 <= T; tt += 2) {
        KT(0, a0f, b0f, a1f, b1f, 0, kt + 128)
        KT(1, a1f, b1f, a0f, b0f, 0, kt + 192)
        kt += 128;
    }
    // peel tiles T-2 and T-1
    KT(0, a0f, b0f, a1f, b1f, 1, 0)
    KT(1, a1f, b1f, a0f, b0f, 2, 0)

    // epilogue: C write (verified C/D map: col = lane&15, row = 4*(l>>4)+j)
    const int crow0 = tm + 16 * wm + 4 * lg;
    const int ccol0 = tn + 16 * wn + lr;
    if constexpr (EPI == 0) {
        unsigned short* C = (unsigned short*)(which ? C1 : C0);
#pragma unroll
        for (int mi = 0; mi < 8; ++mi) {
            const int r0 = crow0 + 32 * mi;
#pragma unroll
            for (int ni = 0; ni < 4; ++ni) {
                const int col = ccol0 + 64 * ni;
                const float bb = bias[col];
#pragma unroll
                for (int j = 0; j < 4; ++j)
                    C[(size_t)(r0 + j) * N + col] = f2bf(acc[mi][ni][j] + bb);
            }
        }
    } else {
        float* C = (float*)(which ? C1 : C0);
#pragma unroll
        for (int mi = 0; mi < 8; ++mi) {
            const int r0 = crow0 + 32 * mi;
#pragma unroll
            for (int ni = 0; ni < 4; ++ni) {
                const int col = ccol0 + 64 * ni;
                const float bb = bias[col];
#pragma unroll
                for (int j = 0; j < 4; ++j) {
                    const size_t idx = (size_t)(r0 + j) * N + col;
                    C[idx] = acc[mi][ni][j] + bb + resid[idx];
                }
            }
        }
    }
}

// ---------------- per-row 16-head cross attention + layernorm ------------------
__device__ __forceinline__ void attn_path(const float* __restrict__ q,
                                          const float* __restrict__ k,
                                          const float* __restrict__ v,
                                          const float* __restrict__ gw,
                                          const float* __restrict__ bw,
                                          unsigned short* __restrict__ out, long b,
                                          float* sS, float* sP, float* red, int t) {
    const int h = t >> 4, gg = t & 15;
    const float* qr = q + h * 65;
    const float* kr = k + gg * 65;
    float s = 0.f;
#pragma unroll
    for (int d = 0; d < 64; ++d) s += qr[d] * kr[d];
    sS[t] = s * 0.125f;
    __syncthreads();
    float mx = -1e30f;
#pragma unroll
    for (int j = 0; j < 16; ++j) mx = fmaxf(mx, sS[h * 16 + j]);
    float sum = 0.f;
#pragma unroll
    for (int j = 0; j < 16; ++j) sum += __expf(sS[h * 16 + j] - mx);
    const float aa = __expf(sS[t] - mx) / sum;
    sP[t] = aa;
    __syncthreads();
    float xs[4];
    float lsum = 0.f, lss = 0.f;
#pragma unroll
    for (int r = 0; r < 4; ++r) {
        const int i = t + 256 * r;
        const int d = i >> 4, hh = i & 15;
        float accv = 0.f;
#pragma unroll
        for (int g2 = 0; g2 < 16; ++g2) accv += sP[hh * 16 + g2] * v[g2 * 65 + d];
        xs[r] = accv;
        lsum += accv;
        lss += accv * accv;
    }
#pragma unroll
    for (int off = 32; off > 0; off >>= 1) {
        lsum += __shfl_down(lsum, off);
        lss += __shfl_down(lss, off);
    }
    if ((t & 63) == 0) {
        red[(t >> 6) * 2] = lsum;
        red[(t >> 6) * 2 + 1] = lss;
    }
    __syncthreads();
    const float tot = red[0] + red[2] + red[4] + red[6];
    const float tot2 = red[1] + red[3] + red[5] + red[7];
    const float mean = tot * (1.f / 1024.f);
    const float var = tot2 * (1.f / 1024.f) - mean * mean;
    const float rstd = rsqrtf(var + EPSV);
#pragma unroll
    for (int r = 0; r < 4; ++r) {
        const int i = t + 256 * r;
        const float y = (xs[r] - mean) * rstd * gw[i] + bw[i];
        out[b * 1024 + i] = f2bf(y);
    }
}

__global__ __launch_bounds__(256) void attn_ln(const unsigned short* __restrict__ qkv_c,
                                               const unsigned short* __restrict__ qkv_m,
                                               const float* __restrict__ g1,
                                               const float* __restrict__ be1,
                                               const float* __restrict__ g2,
                                               const float* __restrict__ be2,
                                               unsigned short* __restrict__ ln1,
                                               unsigned short* __restrict__ ln2) {
    __shared__ float qc[48 * 65];
    __shared__ float qm[48 * 65];
    __shared__ float sS[256];
    __shared__ float sP[256];
    __shared__ float red[8];
    const int t = threadIdx.x;
    const long b = blockIdx.x;

    const unsigned short* rc = qkv_c + b * QKV3;
    const unsigned short* rm = qkv_m + b * QKV3;
#pragma unroll
    for (int it = 0; it < 3; ++it) {
        const int i0 = t * 4 + it * 1024;
        ushort4 vc = *(const ushort4*)(rc + i0);
        ushort4 vm = *(const ushort4*)(rm + i0);
        const int o = i0 + (i0 >> 6);
        qc[o + 0] = bf2f(vc.x); qc[o + 1] = bf2f(vc.y);
        qc[o + 2] = bf2f(vc.z); qc[o + 3] = bf2f(vc.w);
        qm[o + 0] = bf2f(vm.x); qm[o + 1] = bf2f(vm.y);
        qm[o + 2] = bf2f(vm.z); qm[o + 3] = bf2f(vm.w);
    }
    __syncthreads();
    attn_path(qc, qm + 16 * 65, qm + 32 * 65, g1, be1, ln1, b, sS, sP, red, t);
    __syncthreads();
    attn_path(qm, qc + 16 * 65, qc + 32 * 65, g2, be2, ln2, b, sS, sP, red, t);
}

// -------------------------------- launch ---------------------------------------
extern "C" void kernel_launch(void* const* d_in, const int* in_sizes, int n_in,
                              void* d_out, int out_size, void* d_ws, size_t ws_size,
                              hipStream_t stream) {
    const float* cnn    = (const float*)d_in[0];
    const float* mlp    = (const float*)d_in[1];
    const float* W_cqkv = (const float*)d_in[2];
    const float* b_cqkv = (const float*)d_in[3];
    const float* W_mqkv = (const float*)d_in[4];
    const float* b_mqkv = (const float*)d_in[5];
    const float* g1     = (const float*)d_in[6];
    const float* be1    = (const float*)d_in[7];
    const float* g2     = (const float*)d_in[8];
    const float* be2    = (const float*)d_in[9];
    const float* W_cproj = (const float*)d_in[10];
    const float* b_cproj = (const float*)d_in[11];
    const float* W_mproj = (const float*)d_in[12];
    const float* b_mproj = (const float*)d_in[13];
    float* out = (float*)d_out;
    char* ws = (char*)d_ws;

    unsigned short* Abf_c = (unsigned short*)(ws + 0);           // 33,554,432 B
    unsigned short* Abf_m = (unsigned short*)(ws + 33554432);    // 33,554,432 B
    unsigned short* WqT_c = (unsigned short*)(ws + 67108864);    // 12,582,912 B
    unsigned short* WqT_m = (unsigned short*)(ws + 79691776);    // 12,582,912 B
    unsigned short* qkv_c = (unsigned short*)(ws + 92274688);    // 50,331,648 B
    unsigned short* qkv_m = (unsigned short*)(ws + 142606336);   // 50,331,648 B
    unsigned short* ln1   = (unsigned short*)(ws + 0);           // alias Abf_c
    unsigned short* ln2   = (unsigned short*)(ws + 16777216);    // alias Abf_c
    unsigned short* WpT_c = (unsigned short*)(ws + 33554432);    // alias Abf_m
    unsigned short* WpT_m = (unsigned short*)(ws + 37748736);    // alias Abf_m

    dim3 tb(32, 8);

    cvt2_f32_bf16<<<16384, 256, 0, stream>>>(cnn, Abf_c, mlp, Abf_m, (long)NROWS * DIM);
    cvt_transpose<<<dim3(QKV3 / 32, DIM / 32), tb, 0, stream>>>(W_cqkv, WqT_c, DIM, QKV3);
    cvt_transpose<<<dim3(QKV3 / 32, DIM / 32), tb, 0, stream>>>(W_mqkv, WqT_m, DIM, QKV3);

    // fused QKV GEMM pair: (8192x2048)*(2048x3072) x2, grid 768 (= 96 per XCD)
    gemm256<0><<<768, 512, 0, stream>>>(Abf_c, WqT_c, b_cqkv, nullptr, qkv_c,
                                        Abf_m, WqT_m, b_mqkv, nullptr, qkv_m,
                                        NROWS, QKV3, DIM, QKV3 / 256);

    attn_ln<<<NROWS, 256, 0, stream>>>(qkv_c, qkv_m, g1, be1, g2, be2, ln1, ln2);

    cvt_transpose<<<dim3(DIM / 32, HIDN / 32), tb, 0, stream>>>(W_cproj, WpT_c, HIDN, DIM);
    cvt_transpose<<<dim3(DIM / 32, HIDN / 32), tb, 0, stream>>>(W_mproj, WpT_m, HIDN, DIM);

    // fused proj GEMM pair: (8192x1024)*(1024x2048) x2 + bias + residual -> f32
    gemm256<1><<<512, 512, 0, stream>>>(ln1, WpT_c, b_cproj, cnn, out,
                                        ln2, WpT_m, b_mproj, mlp, out + (size_t)NROWS * DIM,
                                        NROWS, DIM, HIDN, DIM / 256);
}

// Round 5
// 665.125 us; speedup vs baseline: 3.7561x; 3.7561x over previous
//
#include <hip/hip_runtime.h>
#include <hip/hip_bf16.h>
#include <cstdint>
#include <cstddef>

// Problem constants
#define NROWS 8192
#define DIM   2048
#define HIDN  1024
#define QKV3  3072
#define EPSV  1e-5f

typedef __attribute__((ext_vector_type(8))) short bf16x8;
typedef __attribute__((ext_vector_type(4))) float f32x4;

__device__ __forceinline__ unsigned short f2bf(float x) {
    __hip_bfloat16 h = __float2bfloat16(x);
    return *reinterpret_cast<unsigned short*>(&h);
}
__device__ __forceinline__ float bf2f(unsigned short u) {
    return __uint_as_float((unsigned)u << 16);
}

__device__ __forceinline__ void gload_lds16(const void* g, void* l) {
    __builtin_amdgcn_global_load_lds(
        (const __attribute__((address_space(1))) void*)g,
        (__attribute__((address_space(3))) void*)l, 16, 0, 0);
}

template <int N> __device__ __forceinline__ void vmwait() {
    if constexpr (N == 6)      asm volatile("s_waitcnt vmcnt(6)" ::: "memory");
    else if constexpr (N == 4) asm volatile("s_waitcnt vmcnt(4)" ::: "memory");
    else if constexpr (N == 2) asm volatile("s_waitcnt vmcnt(2)" ::: "memory");
    else if constexpr (N == 0) asm volatile("s_waitcnt vmcnt(0)" ::: "memory");
}
__device__ __forceinline__ void barrier_mem() {
    asm volatile("s_barrier" ::: "memory");
}

// ---------------- f32 -> bf16 elementwise convert, two tensors -----------------
__global__ __launch_bounds__(256) void cvt2_f32_bf16(const float* __restrict__ inA,
                                                     unsigned short* __restrict__ outA,
                                                     const float* __restrict__ inB,
                                                     unsigned short* __restrict__ outB,
                                                     long n) {
    const int which = blockIdx.x >> 13;           // 8192 blocks per tensor
    const long bid = blockIdx.x & 8191;
    const float* in = which ? inB : inA;
    unsigned short* out = which ? outB : outA;
    long base = (bid * 256 + threadIdx.x) * 8;
    if (base >= n) return;
    float4 a = *(const float4*)(in + base);
    float4 b = *(const float4*)(in + base + 4);
    uint4 r;
    r.x = (unsigned)f2bf(a.x) | ((unsigned)f2bf(a.y) << 16);
    r.y = (unsigned)f2bf(a.z) | ((unsigned)f2bf(a.w) << 16);
    r.z = (unsigned)f2bf(b.x) | ((unsigned)f2bf(b.y) << 16);
    r.w = (unsigned)f2bf(b.z) | ((unsigned)f2bf(b.w) << 16);
    *(uint4*)(out + base) = r;
}

// ---------------- f32 [R][C] -> bf16 [C][R] transpose+convert ------------------
__global__ __launch_bounds__(256) void cvt_transpose(const float* __restrict__ in,
                                                     unsigned short* __restrict__ out,
                                                     int R, int C) {
    __shared__ float tile[32][33];
    const int tx = threadIdx.x, ty = threadIdx.y;   // block (32,8)
    const int c0 = blockIdx.x * 32, r0 = blockIdx.y * 32;
#pragma unroll
    for (int i = 0; i < 4; ++i)
        tile[ty + i * 8][tx] = in[(size_t)(r0 + ty + i * 8) * C + c0 + tx];
    __syncthreads();
#pragma unroll
    for (int i = 0; i < 4; ++i)
        out[(size_t)(c0 + ty + i * 8) * R + r0 + tx] = f2bf(tile[tx][ty + i * 8]);
}

// ====== 256x256 8-phase bf16 GEMM, 1-phase-ahead fragment pipeline =============
// 512 thr = 8 waves (2M x 4N interleaved), BK=64, LDS 128 KiB double-buffered,
// T2 XOR swizzle. Regions: Ah0=A rows 0-127 (frags aL), Ah1=128-255 (aH),
// Bh0 (b01), Bh1 (b23). Per phase: [stage 2 gloads][vmcnt(6)][barrier]
// [ds_read frags needed next phase + 16 MFMA][barrier].
// Reads:  b23(t)@ph1, aH(t)@ph2, b01(t+1)@ph3, aL(t+1)@ph4.
// Stages: Ah0(t+1)@ph1, Bh1(t+1)@ph2, Ah1(t+1)@ph3, Bh0(t+2)@ph4.
// Every stage lands 3 phases before its consumer read -> uniform vmcnt(6).

#define STG(Gp, c0c, c1c, ARR, BUF, HALF, KTS)                                 \
    gload_lds16((Gp) + (c0c) + (KTS), (char*)&ARR[BUF][(HALF) * 8192] + dO0);  \
    gload_lds16((Gp) + (c1c) + (KTS), (char*)&ARR[BUF][(HALF) * 8192] + dO1);

#define RDAL(BUF)                                                              \
    _Pragma("unroll") for (int m_ = 0; m_ < 4; ++m_) {                         \
        const char* p_ = (const char*)&sA[BUF][0] + rowA + m_ * 4096;          \
        aL[m_][0] = *(const bf16x8*)(p_ + o0);                                 \
        aL[m_][1] = *(const bf16x8*)(p_ + (o0 ^ 64));                          \
    }
#define RDAH(BUF)                                                              \
    _Pragma("unroll") for (int m_ = 0; m_ < 4; ++m_) {                         \
        const char* p_ = (const char*)&sA[BUF][0] + rowA + (4 + m_) * 4096;    \
        aH[m_][0] = *(const bf16x8*)(p_ + o0);                                 \
        aH[m_][1] = *(const bf16x8*)(p_ + (o0 ^ 64));                          \
    }
#define RDB01(DST, BUF)                                                        \
    _Pragma("unroll") for (int n_ = 0; n_ < 2; ++n_) {                         \
        const char* p_ = (const char*)&sB[BUF][0] + rowB + n_ * 8192;          \
        DST[n_][0] = *(const bf16x8*)(p_ + o0);                                \
        DST[n_][1] = *(const bf16x8*)(p_ + (o0 ^ 64));                         \
    }
#define RDB23(BUF)                                                             \
    _Pragma("unroll") for (int n_ = 0; n_ < 2; ++n_) {                         \
        const char* p_ = (const char*)&sB[BUF][0] + rowB + (2 + n_) * 8192;    \
        b23[n_][0] = *(const bf16x8*)(p_ + o0);                                \
        b23[n_][1] = *(const bf16x8*)(p_ + (o0 ^ 64));                         \
    }

// kk outermost: 8 independent MFMAs between dependent accumulate pairs
#define QUADQ(AR, BR, mq, nq)                                                  \
    __builtin_amdgcn_s_setprio(1);                                             \
    _Pragma("unroll") for (int kk_ = 0; kk_ < 2; ++kk_)                        \
    _Pragma("unroll") for (int n_ = 0; n_ < 2; ++n_)                           \
    _Pragma("unroll") for (int m_ = 0; m_ < 4; ++m_)                           \
        acc[(mq) + m_][(nq) + n_] = __builtin_amdgcn_mfma_f32_16x16x32_bf16(   \
            AR[m_][kk_], BR[n_][kk_], acc[(mq) + m_][(nq) + n_], 0, 0, 0);     \
    __builtin_amdgcn_s_setprio(0);

// MODE 0 steady | MODE 1 tile T-2 (no ph4 stage; waits 6,6,6,4)
// MODE 2 tile T-1 (no stages, no next-tile reads; waits 2,0,-,-)
#define TILE(BUF, B01X, B01Y, MODE, KN, KN2)                                   \
    /* ph1 */                                                                  \
    if constexpr ((MODE) <= 1) { STG(A, gA0c0, gA0c1, sA, (BUF) ^ 1, 0, KN) }  \
    if constexpr ((MODE) <= 1) vmwait<6>(); else vmwait<2>();                  \
    barrier_mem();                                                             \
    RDB23(BUF)                                                                 \
    QUADQ(aL, B01X, 0, 0);                                                     \
    barrier_mem();                                                             \
    /* ph2 */                                                                  \
    if constexpr ((MODE) <= 1) { STG(Bt, gB1c0, gB1c1, sB, (BUF) ^ 1, 1, KN) } \
    if constexpr ((MODE) <= 1) vmwait<6>(); else vmwait<0>();                  \
    barrier_mem();                                                             \
    RDAH(BUF)                                                                  \
    QUADQ(aL, b23, 0, 2);                                                      \
    barrier_mem();                                                             \
    /* ph3 */                                                                  \
    if constexpr ((MODE) <= 1) { STG(A, gA1c0, gA1c1, sA, (BUF) ^ 1, 1, KN) }  \
    if constexpr ((MODE) <= 1) vmwait<6>();                                    \
    barrier_mem();                                                             \
    if constexpr ((MODE) <= 1) { RDB01(B01Y, (BUF) ^ 1) }                      \
    QUADQ(aH, B01X, 4, 0);                                                     \
    barrier_mem();                                                             \
    /* ph4 */                                                                  \
    if constexpr ((MODE) == 0) { STG(Bt, gB0c0, gB0c1, sB, BUF, 0, KN2) }      \
    if constexpr ((MODE) == 0) vmwait<6>();                                    \
    if constexpr ((MODE) == 1) vmwait<4>();                                    \
    barrier_mem();                                                             \
    if constexpr ((MODE) <= 1) { RDAL((BUF) ^ 1) }                             \
    QUADQ(aH, b23, 4, 2);                                                      \
    barrier_mem();

template <int EPI>
__global__ __launch_bounds__(512, 1) void gemm256(
    const unsigned short* __restrict__ A0, const unsigned short* __restrict__ B0t,
    const float* __restrict__ bias0, const float* __restrict__ res0, void* __restrict__ C0,
    const unsigned short* __restrict__ A1, const unsigned short* __restrict__ B1t,
    const float* __restrict__ bias1, const float* __restrict__ res1, void* __restrict__ C1,
    int M, int N, int K, int nbx) {
    __shared__ __align__(16) short sA[2][16384];
    __shared__ __align__(16) short sB[2][16384];

    const int tid = threadIdx.x;
    // bijective XCD swizzle (gridDim.x % 8 == 0 for all our launches)
    const int nwg = gridDim.x;
    const int ob = blockIdx.x;
    const int swz = (ob & 7) * (nwg >> 3) + (ob >> 3);
    const int per = nbx * (M >> 8);
    const int which = swz >= per ? 1 : 0;
    const int rem = swz - which * per;
    const int by = rem / nbx, bx = rem % nbx;
    const int tm = by << 8, tn = bx << 8;

    const unsigned short* __restrict__ A  = which ? A1 : A0;
    const unsigned short* __restrict__ Bt = which ? B1t : B0t;
    const float* __restrict__ bias  = which ? bias1 : bias0;
    const float* __restrict__ resid = which ? res1 : res0;

    const int w = tid >> 6, l = tid & 63;
    const int wm = w >> 2, wn = w & 3;           // 2 x 4 waves
    const int lg = l >> 4, lr = l & 15;
    const int o0 = (lg ^ (lr & 7)) << 4;         // swizzled k-slot byte offset
    const int rowA = (16 * wm + lr) << 7;        // byte offset of lane's A row
    const int rowB = (16 * wn + lr) << 7;

    // hoisted per-thread staging constants (element offsets; +K-offset per call)
    const int rr0 = tid >> 3;
    const int jj0 = ((tid & 7) ^ (rr0 & 7)) * 8;
    const int cc1 = 512 + tid, rr1 = cc1 >> 3;
    const int jj1 = ((cc1 & 7) ^ (rr1 & 7)) * 8;
    const int gA0c0 = (tm + rr0) * K + jj0;
    const int gA0c1 = (tm + rr1) * K + jj1;
    const int gA1c0 = (tm + 128 + rr0) * K + jj0;
    const int gA1c1 = (tm + 128 + rr1) * K + jj1;
    const int gB0c0 = (tn + rr0) * K + jj0;
    const int gB0c1 = (tn + rr1) * K + jj1;
    const int gB1c0 = (tn + 128 + rr0) * K + jj0;
    const int gB1c1 = (tn + 128 + rr1) * K + jj1;
    const int dO0 = (tid & 0x1C0) * 16;
    const int dO1 = (512 + (tid & 0x1C0)) * 16;

    f32x4 acc[8][4] = {};
    bf16x8 aL[4][2], aH[4][2], b01e[2][2], b01o[2][2], b23[2][2];

    const int T = K >> 6;                        // K-tiles (even, >= 4)

    // prologue: stage tile0 {Bh0,Ah0,Bh1,Ah1} + Bh0(1); read b01e(0), aL(0)
    STG(Bt, gB0c0, gB0c1, sB, 0, 0, 0)
    STG(A,  gA0c0, gA0c1, sA, 0, 0, 0)
    STG(Bt, gB1c0, gB1c1, sB, 0, 1, 0)
    STG(A,  gA1c0, gA1c1, sA, 0, 1, 0)
    STG(Bt, gB0c0, gB0c1, sB, 1, 0, 64)
    vmwait<6>();                                 // Bh0(0)+Ah0(0) landed
    barrier_mem();
    RDB01(b01e, 0)
    RDAL(0)

    int kt = 0;
    for (; kt < K - 128; kt += 128) {
        TILE(0, b01e, b01o, 0, kt + 64, kt + 128)
        TILE(1, b01o, b01e, 0, kt + 128, kt + 192)
    }
    // peel tiles T-2 (buf0, even -> b01e) and T-1 (buf1, b01o)
    TILE(0, b01e, b01o, 1, kt + 64, 0)
    TILE(1, b01o, b01e, 2, 0, 0)

    // epilogue: C write (verified C/D map: col = lane&15, row = 4*(l>>4)+j)
    const int crow0 = tm + 16 * wm + 4 * lg;
    const int ccol0 = tn + 16 * wn + lr;
    if constexpr (EPI == 0) {
        unsigned short* C = (unsigned short*)(which ? C1 : C0);
#pragma unroll
        for (int mi = 0; mi < 8; ++mi) {
            const int r0 = crow0 + 32 * mi;
#pragma unroll
            for (int ni = 0; ni < 4; ++ni) {
                const int col = ccol0 + 64 * ni;
                const float bb = bias[col];
#pragma unroll
                for (int j = 0; j < 4; ++j)
                    C[(size_t)(r0 + j) * N + col] = f2bf(acc[mi][ni][j] + bb);
            }
        }
    } else {
        float* C = (float*)(which ? C1 : C0);
#pragma unroll
        for (int mi = 0; mi < 8; ++mi) {
            const int r0 = crow0 + 32 * mi;
#pragma unroll
            for (int ni = 0; ni < 4; ++ni) {
                const int col = ccol0 + 64 * ni;
                const float bb = bias[col];
#pragma unroll
                for (int j = 0; j < 4; ++j) {
                    const size_t idx = (size_t)(r0 + j) * N + col;
                    C[idx] = acc[mi][ni][j] + bb + resid[idx];
                }
            }
        }
    }
}

// ---------------- per-row 16-head cross attention + layernorm ------------------
__device__ __forceinline__ void attn_path(const float* __restrict__ q,
                                          const float* __restrict__ k,
                                          const float* __restrict__ v,
                                          const float* __restrict__ gw,
                                          const float* __restrict__ bw,
                                          unsigned short* __restrict__ out, long b,
                                          float* sS, float* sP, float* red, int t) {
    const int h = t >> 4, gg = t & 15;
    const float* qr = q + h * 65;
    const float* kr = k + gg * 65;
    float s = 0.f;
#pragma unroll
    for (int d = 0; d < 64; ++d) s += qr[d] * kr[d];
    sS[t] = s * 0.125f;
    __syncthreads();
    float mx = -1e30f;
#pragma unroll
    for (int j = 0; j < 16; ++j) mx = fmaxf(mx, sS[h * 16 + j]);
    float sum = 0.f;
#pragma unroll
    for (int j = 0; j < 16; ++j) sum += __expf(sS[h * 16 + j] - mx);
    const float aa = __expf(sS[t] - mx) / sum;
    sP[t] = aa;
    __syncthreads();
    float xs[4];
    float lsum = 0.f, lss = 0.f;
#pragma unroll
    for (int r = 0; r < 4; ++r) {
        const int i = t + 256 * r;
        const int d = i >> 4, hh = i & 15;
        float accv = 0.f;
#pragma unroll
        for (int g2 = 0; g2 < 16; ++g2) accv += sP[hh * 16 + g2] * v[g2 * 65 + d];
        xs[r] = accv;
        lsum += accv;
        lss += accv * accv;
    }
#pragma unroll
    for (int off = 32; off > 0; off >>= 1) {
        lsum += __shfl_down(lsum, off);
        lss += __shfl_down(lss, off);
    }
    if ((t & 63) == 0) {
        red[(t >> 6) * 2] = lsum;
        red[(t >> 6) * 2 + 1] = lss;
    }
    __syncthreads();
    const float tot = red[0] + red[2] + red[4] + red[6];
    const float tot2 = red[1] + red[3] + red[5] + red[7];
    const float mean = tot * (1.f / 1024.f);
    const float var = tot2 * (1.f / 1024.f) - mean * mean;
    const float rstd = rsqrtf(var + EPSV);
#pragma unroll
    for (int r = 0; r < 4; ++r) {
        const int i = t + 256 * r;
        const float y = (xs[r] - mean) * rstd * gw[i] + bw[i];
        out[b * 1024 + i] = f2bf(y);
    }
}

__global__ __launch_bounds__(256) void attn_ln(const unsigned short* __restrict__ qkv_c,
                                               const unsigned short* __restrict__ qkv_m,
                                               const float* __restrict__ g1,
                                               const float* __restrict__ be1,
                                               const float* __restrict__ g2,
                                               const float* __restrict__ be2,
                                               unsigned short* __restrict__ ln1,
                                               unsigned short* __restrict__ ln2) {
    __shared__ float qc[48 * 65];
    __shared__ float qm[48 * 65];
    __shared__ float sS[256];
    __shared__ float sP[256];
    __shared__ float red[8];
    const int t = threadIdx.x;
    const long b = blockIdx.x;

    const unsigned short* rc = qkv_c + b * QKV3;
    const unsigned short* rm = qkv_m + b * QKV3;
#pragma unroll
    for (int it = 0; it < 3; ++it) {
        const int i0 = t * 4 + it * 1024;
        ushort4 vc = *(const ushort4*)(rc + i0);
        ushort4 vm = *(const ushort4*)(rm + i0);
        const int o = i0 + (i0 >> 6);
        qc[o + 0] = bf2f(vc.x); qc[o + 1] = bf2f(vc.y);
        qc[o + 2] = bf2f(vc.z); qc[o + 3] = bf2f(vc.w);
        qm[o + 0] = bf2f(vm.x); qm[o + 1] = bf2f(vm.y);
        qm[o + 2] = bf2f(vm.z); qm[o + 3] = bf2f(vm.w);
    }
    __syncthreads();
    attn_path(qc, qm + 16 * 65, qm + 32 * 65, g1, be1, ln1, b, sS, sP, red, t);
    __syncthreads();
    attn_path(qm, qc + 16 * 65, qc + 32 * 65, g2, be2, ln2, b, sS, sP, red, t);
}

// -------------------------------- launch ---------------------------------------
extern "C" void kernel_launch(void* const* d_in, const int* in_sizes, int n_in,
                              void* d_out, int out_size, void* d_ws, size_t ws_size,
                              hipStream_t stream) {
    const float* cnn    = (const float*)d_in[0];
    const float* mlp    = (const float*)d_in[1];
    const float* W_cqkv = (const float*)d_in[2];
    const float* b_cqkv = (const float*)d_in[3];
    const float* W_mqkv = (const float*)d_in[4];
    const float* b_mqkv = (const float*)d_in[5];
    const float* g1     = (const float*)d_in[6];
    const float* be1    = (const float*)d_in[7];
    const float* g2     = (const float*)d_in[8];
    const float* be2    = (const float*)d_in[9];
    const float* W_cproj = (const float*)d_in[10];
    const float* b_cproj = (const float*)d_in[11];
    const float* W_mproj = (const float*)d_in[12];
    const float* b_mproj = (const float*)d_in[13];
    float* out = (float*)d_out;
    char* ws = (char*)d_ws;

    unsigned short* Abf_c = (unsigned short*)(ws + 0);           // 33,554,432 B
    unsigned short* Abf_m = (unsigned short*)(ws + 33554432);    // 33,554,432 B
    unsigned short* WqT_c = (unsigned short*)(ws + 67108864);    // 12,582,912 B
    unsigned short* WqT_m = (unsigned short*)(ws + 79691776);    // 12,582,912 B
    unsigned short* qkv_c = (unsigned short*)(ws + 92274688);    // 50,331,648 B
    unsigned short* qkv_m = (unsigned short*)(ws + 142606336);   // 50,331,648 B
    unsigned short* ln1   = (unsigned short*)(ws + 0);           // alias Abf_c
    unsigned short* ln2   = (unsigned short*)(ws + 16777216);    // alias Abf_c
    unsigned short* WpT_c = (unsigned short*)(ws + 33554432);    // alias Abf_m
    unsigned short* WpT_m = (unsigned short*)(ws + 37748736);    // alias Abf_m

    dim3 tb(32, 8);

    cvt2_f32_bf16<<<16384, 256, 0, stream>>>(cnn, Abf_c, mlp, Abf_m, (long)NROWS * DIM);
    cvt_transpose<<<dim3(QKV3 / 32, DIM / 32), tb, 0, stream>>>(W_cqkv, WqT_c, DIM, QKV3);
    cvt_transpose<<<dim3(QKV3 / 32, DIM / 32), tb, 0, stream>>>(W_mqkv, WqT_m, DIM, QKV3);

    // fused QKV GEMM pair: (8192x2048)*(2048x3072) x2, grid 768 (= 96 per XCD)
    gemm256<0><<<768, 512, 0, stream>>>(Abf_c, WqT_c, b_cqkv, nullptr, qkv_c,
                                        Abf_m, WqT_m, b_mqkv, nullptr, qkv_m,
                                        NROWS, QKV3, DIM, QKV3 / 256);

    attn_ln<<<NROWS, 256, 0, stream>>>(qkv_c, qkv_m, g1, be1, g2, be2, ln1, ln2);

    cvt_transpose<<<dim3(DIM / 32, HIDN / 32), tb, 0, stream>>>(W_cproj, WpT_c, HIDN, DIM);
    cvt_transpose<<<dim3(DIM / 32, HIDN / 32), tb, 0, stream>>>(W_mproj, WpT_m, HIDN, DIM);

    // fused proj GEMM pair: (8192x1024)*(1024x2048) x2 + bias + residual -> f32
    gemm256<1><<<512, 512, 0, stream>>>(ln1, WpT_c, b_cproj, cnn, out,
                                        ln2, WpT_m, b_mproj, mlp, out + (size_t)NROWS * DIM,
                                        NROWS, DIM, HIDN, DIM / 256);
}

// Round 6
// 421.574 us; speedup vs baseline: 5.9261x; 1.5777x over previous
//
#include <hip/hip_runtime.h>
#include <hip/hip_bf16.h>
#include <cstdint>
#include <cstddef>

// Problem constants
#define NROWS 8192
#define DIM   2048
#define HIDN  1024
#define QKV3  3072
#define EPSV  1e-5f

typedef __attribute__((ext_vector_type(8))) short bf16x8;
typedef __attribute__((ext_vector_type(4))) float f32x4;

__device__ __forceinline__ unsigned short f2bf(float x) {
    __hip_bfloat16 h = __float2bfloat16(x);
    return *reinterpret_cast<unsigned short*>(&h);
}
__device__ __forceinline__ float bf2f(unsigned short u) {
    return __uint_as_float((unsigned)u << 16);
}

__device__ __forceinline__ void gload_lds16(const void* g, void* l) {
    __builtin_amdgcn_global_load_lds(
        (const __attribute__((address_space(1))) void*)g,
        (__attribute__((address_space(3))) void*)l, 16, 0, 0);
}

template <int N> __device__ __forceinline__ void vmwait() {
    if constexpr (N == 8)      asm volatile("s_waitcnt vmcnt(8)" ::: "memory");
    else if constexpr (N == 4) asm volatile("s_waitcnt vmcnt(4)" ::: "memory");
    else if constexpr (N == 2) asm volatile("s_waitcnt vmcnt(2)" ::: "memory");
    else if constexpr (N == 0) asm volatile("s_waitcnt vmcnt(0)" ::: "memory");
}
__device__ __forceinline__ void barrier_mem() {
    asm volatile("s_barrier" ::: "memory");
}

// ---------------- f32 -> bf16 elementwise convert, two tensors -----------------
__global__ __launch_bounds__(256) void cvt2_f32_bf16(const float* __restrict__ inA,
                                                     unsigned short* __restrict__ outA,
                                                     const float* __restrict__ inB,
                                                     unsigned short* __restrict__ outB,
                                                     long n) {
    const int which = blockIdx.x >> 13;           // 8192 blocks per tensor
    const long bid = blockIdx.x & 8191;
    const float* in = which ? inB : inA;
    unsigned short* out = which ? outB : outA;
    long base = (bid * 256 + threadIdx.x) * 8;
    if (base >= n) return;
    float4 a = *(const float4*)(in + base);
    float4 b = *(const float4*)(in + base + 4);
    uint4 r;
    r.x = (unsigned)f2bf(a.x) | ((unsigned)f2bf(a.y) << 16);
    r.y = (unsigned)f2bf(a.z) | ((unsigned)f2bf(a.w) << 16);
    r.z = (unsigned)f2bf(b.x) | ((unsigned)f2bf(b.y) << 16);
    r.w = (unsigned)f2bf(b.z) | ((unsigned)f2bf(b.w) << 16);
    *(uint4*)(out + base) = r;
}

// ---------------- f32 [R][C] -> bf16 [C][R] transpose+convert ------------------
__global__ __launch_bounds__(256) void cvt_transpose(const float* __restrict__ in,
                                                     unsigned short* __restrict__ out,
                                                     int R, int C) {
    __shared__ float tile[32][33];
    const int tx = threadIdx.x, ty = threadIdx.y;   // block (32,8)
    const int c0 = blockIdx.x * 32, r0 = blockIdx.y * 32;
#pragma unroll
    for (int i = 0; i < 4; ++i)
        tile[ty + i * 8][tx] = in[(size_t)(r0 + ty + i * 8) * C + c0 + tx];
    __syncthreads();
#pragma unroll
    for (int i = 0; i < 4; ++i)
        out[(size_t)(c0 + ty + i * 8) * R + r0 + tx] = f2bf(tile[tx][ty + i * 8]);
}

// ============== 256x256 8-phase bf16 GEMM (C = A * Bt^T + bias [+resid]) =======
// 512 thr = 8 waves (2M x 4N), BK=64, LDS 128 KiB double-buffered, T2 XOR
// swizzle. ONE barrier per phase: [stage][vmcnt][s_barrier][ds_reads][16 MFMA]
// -> early waves' MFMA overlaps late waves' LDS reads (no post-QUAD barrier;
// WAR gaps all >= 2 barriers, verified region-by-region).
// Stages (tile t): ph1 Bh1(t+1) | ph2 Ah1(t+1) | ph3 Ah0(t+2) | ph4 Bh0(t+2).
// Reads (post-barrier): ph1 a0-3(t) | ph2 b2-3(t) | ph3 a4-7(t) | ph4 b01(t+1).
// Waits (pre-barrier): ph1 vm8 (certifies Bh1(t)), ph2 vm8 (Ah1(t)),
// ph4 vm8 (Ah0/Bh0(t+1)).  Tails: MODE1 {8,8,-,4}, MODE2 {2,0,-,-}.

__device__ __forceinline__ void stage_half(const unsigned short* __restrict__ G,
                                           int ldK, int rowBase, int kt,
                                           short* ldsHalf, int tid) {
#pragma unroll
    for (int i = 0; i < 2; ++i) {
        const int c = i * 512 + tid;            // 16-byte chunk index (0..1023)
        const int r = c >> 3;                   // row 0..127
        const int jl = (c & 7) ^ (r & 7);       // logical k-slot for this phys slot
        const unsigned short* src = G + (size_t)(rowBase + r) * ldK + kt + jl * 8;
        char* dst = (char*)ldsHalf + (size_t)((i * 512 + (tid & 0x1C0)) * 16);
        gload_lds16(src, dst);
    }
}

__device__ __forceinline__ void load_a4(const short* sAb, int rowA, int o0, int mbase,
                                        bf16x8 (&a)[4][2]) {
#pragma unroll
    for (int m = 0; m < 4; ++m) {
        const char* p = (const char*)sAb + rowA + (mbase + m) * 4096;
        a[m][0] = *(const bf16x8*)(p + o0);
        a[m][1] = *(const bf16x8*)(p + (o0 ^ 64));
    }
}
__device__ __forceinline__ void load_b2(const short* sBb, int rowB, int o0, int nbase,
                                        bf16x8 (&b)[4][2]) {
#pragma unroll
    for (int n = 0; n < 2; ++n) {
        const char* p = (const char*)sBb + rowB + (nbase + n) * 8192;
        b[nbase + n][0] = *(const bf16x8*)(p + o0);
        b[nbase + n][1] = *(const bf16x8*)(p + (o0 ^ 64));
    }
}

// kk OUTERMOST: 8 independent MFMAs between dependent accumulate pairs
#define QUAD(mq, nq)                                                          \
    __builtin_amdgcn_s_setprio(1);                                            \
    _Pragma("unroll") for (int kk_ = 0; kk_ < 2; ++kk_)                       \
    _Pragma("unroll") for (int n_ = 0; n_ < 2; ++n_)                          \
    _Pragma("unroll") for (int m_ = 0; m_ < 4; ++m_)                          \
        acc[(mq) + m_][(nq) + n_] = __builtin_amdgcn_mfma_f32_16x16x32_bf16(  \
            a[m_][kk_], b[(nq) + n_][kk_], acc[(mq) + m_][(nq) + n_], 0, 0, 0); \
    __builtin_amdgcn_s_setprio(0);

// MODE 0: steady | MODE 1: tile T-2 (stage ph1/ph2 only; ph4 vm4)
// MODE 2: tile T-1 (no stages; ph1 vm2, ph2 vm0; no ph4 pre-read)
#define KTILE(BUF, MODE, KT1, KT2)                                            \
    /* ph1 */                                                                 \
    if constexpr ((MODE) <= 1)                                                \
        stage_half(Bt, K, tn + 128, (KT1), &sB[(BUF) ^ 1][8192], tid);        \
    if constexpr ((MODE) == 2) { vmwait<2>(); } else { vmwait<8>(); }         \
    barrier_mem();                                                            \
    load_a4(&sA[BUF][0], rowA, o0, 0, a);                                     \
    QUAD(0, 0);                                                               \
    /* ph2 */                                                                 \
    if constexpr ((MODE) <= 1)                                                \
        stage_half(A, K, tm + 128, (KT1), &sA[(BUF) ^ 1][8192], tid);         \
    if constexpr ((MODE) == 2) { vmwait<0>(); } else { vmwait<8>(); }         \
    barrier_mem();                                                            \
    load_b2(&sB[BUF][0], rowB, o0, 2, b);                                     \
    QUAD(0, 2);                                                               \
    /* ph3 */                                                                 \
    if constexpr ((MODE) == 0)                                                \
        stage_half(A, K, tm, (KT2), &sA[BUF][0], tid);                        \
    barrier_mem();                                                            \
    load_a4(&sA[BUF][0], rowA, o0, 4, a);                                     \
    QUAD(4, 0);                                                               \
    /* ph4 */                                                                 \
    if constexpr ((MODE) == 0) {                                              \
        stage_half(Bt, K, tn, (KT2), &sB[BUF][0], tid);                       \
        vmwait<8>();                                                          \
    }                                                                         \
    if constexpr ((MODE) == 1) { vmwait<4>(); }                               \
    barrier_mem();                                                            \
    if constexpr ((MODE) <= 1)                                                \
        load_b2(&sB[(BUF) ^ 1][0], rowB, o0, 0, b);  /* b01(t+1) pre-read */  \
    QUAD(4, 2);

template <int EPI>
__global__ __launch_bounds__(512, 2) void gemm256(
    const unsigned short* __restrict__ A0, const unsigned short* __restrict__ B0t,
    const float* __restrict__ bias0, const float* __restrict__ res0, void* __restrict__ C0,
    const unsigned short* __restrict__ A1, const unsigned short* __restrict__ B1t,
    const float* __restrict__ bias1, const float* __restrict__ res1, void* __restrict__ C1,
    int M, int N, int K, int nbx) {
    __shared__ __align__(16) short sA[2][16384];
    __shared__ __align__(16) short sB[2][16384];

    const int tid = threadIdx.x;
    // bijective XCD swizzle (gridDim.x % 8 == 0 for all our launches)
    const int nwg = gridDim.x;
    const int ob = blockIdx.x;
    const int swz = (ob & 7) * (nwg >> 3) + (ob >> 3);
    const int per = nbx * (M >> 8);
    const int which = swz >= per ? 1 : 0;
    const int rem = swz - which * per;
    const int by = rem / nbx, bx = rem % nbx;
    const int tm = by << 8, tn = bx << 8;

    const unsigned short* __restrict__ A  = which ? A1 : A0;
    const unsigned short* __restrict__ Bt = which ? B1t : B0t;
    const float* __restrict__ bias  = which ? bias1 : bias0;
    const float* __restrict__ resid = which ? res1 : res0;

    const int w = tid >> 6, l = tid & 63;
    const int wm = w >> 2, wn = w & 3;           // 2 x 4 waves
    const int lg = l >> 4, lr = l & 15;
    const int o0 = (lg ^ (lr & 7)) << 4;         // swizzled k-slot byte offset
    const int rowA = (16 * wm + lr) << 7;        // byte offset of lane's A row
    const int rowB = (16 * wn + lr) << 7;

    f32x4 acc[8][4] = {};
    bf16x8 a[4][2], b[4][2];

    const int T = K >> 6;                        // K-tiles (even, >= 4)

    // prologue: halves Ah0(0),Bh0(0),Bh1(0),Ah1(0),Ah0(1),Bh0(1); vm8 drains
    // Ah0(0)+Bh0(0); barrier certifies for all waves; pre-read b01(0).
    stage_half(A,  K, tm,       0,  &sA[0][0],    tid);
    stage_half(Bt, K, tn,       0,  &sB[0][0],    tid);
    stage_half(Bt, K, tn + 128, 0,  &sB[0][8192], tid);
    stage_half(A,  K, tm + 128, 0,  &sA[0][8192], tid);
    stage_half(A,  K, tm,       64, &sA[1][0],    tid);
    stage_half(Bt, K, tn,       64, &sB[1][0],    tid);
    vmwait<8>();
    barrier_mem();
    load_b2(&sB[0][0], rowB, o0, 0, b);          // b01(0)

    int kt = 0;
    for (int tt = 0; tt + 4 <= T; tt += 2) {
        KTILE(0, 0, kt + 64, kt + 128);
        KTILE(1, 0, kt + 128, kt + 192);
        kt += 128;
    }
    // peel tiles T-2 (buf0) and T-1 (buf1)
    KTILE(0, 1, kt + 64, 0);
    KTILE(1, 2, 0, 0);

    // epilogue: C write (verified C/D map: col = lane&15, row = 4*(l>>4)+j)
    const int crow0 = tm + 16 * wm + 4 * lg;
    const int ccol0 = tn + 16 * wn + lr;
    if constexpr (EPI == 0) {
        unsigned short* C = (unsigned short*)(which ? C1 : C0);
#pragma unroll
        for (int mi = 0; mi < 8; ++mi) {
            const int r0 = crow0 + 32 * mi;
#pragma unroll
            for (int ni = 0; ni < 4; ++ni) {
                const int col = ccol0 + 64 * ni;
                const float bb = bias[col];
#pragma unroll
                for (int j = 0; j < 4; ++j)
                    C[(size_t)(r0 + j) * N + col] = f2bf(acc[mi][ni][j] + bb);
            }
        }
    } else {
        float* C = (float*)(which ? C1 : C0);
#pragma unroll
        for (int mi = 0; mi < 8; ++mi) {
            const int r0 = crow0 + 32 * mi;
#pragma unroll
            for (int ni = 0; ni < 4; ++ni) {
                const int col = ccol0 + 64 * ni;
                const float bb = bias[col];
#pragma unroll
                for (int j = 0; j < 4; ++j) {
                    const size_t idx = (size_t)(r0 + j) * N + col;
                    C[idx] = acc[mi][ni][j] + bb + resid[idx];
                }
            }
        }
    }
}

// ---------------- per-row 16-head cross attention + layernorm ------------------
__device__ __forceinline__ void attn_path(const float* __restrict__ q,
                                          const float* __restrict__ k,
                                          const float* __restrict__ v,
                                          const float* __restrict__ gw,
                                          const float* __restrict__ bw,
                                          unsigned short* __restrict__ out, long b,
                                          float* sS, float* sP, float* red, int t) {
    const int h = t >> 4, gg = t & 15;
    const float* qr = q + h * 65;
    const float* kr = k + gg * 65;
    float s = 0.f;
#pragma unroll
    for (int d = 0; d < 64; ++d) s += qr[d] * kr[d];
    sS[t] = s * 0.125f;
    __syncthreads();
    float mx = -1e30f;
#pragma unroll
    for (int j = 0; j < 16; ++j) mx = fmaxf(mx, sS[h * 16 + j]);
    float sum = 0.f;
#pragma unroll
    for (int j = 0; j < 16; ++j) sum += __expf(sS[h * 16 + j] - mx);
    const float aa = __expf(sS[t] - mx) / sum;
    sP[t] = aa;
    __syncthreads();
    float xs[4];
    float lsum = 0.f, lss = 0.f;
#pragma unroll
    for (int r = 0; r < 4; ++r) {
        const int i = t + 256 * r;
        const int d = i >> 4, hh = i & 15;
        float accv = 0.f;
#pragma unroll
        for (int g2 = 0; g2 < 16; ++g2) accv += sP[hh * 16 + g2] * v[g2 * 65 + d];
        xs[r] = accv;
        lsum += accv;
        lss += accv * accv;
    }
#pragma unroll
    for (int off = 32; off > 0; off >>= 1) {
        lsum += __shfl_down(lsum, off);
        lss += __shfl_down(lss, off);
    }
    if ((t & 63) == 0) {
        red[(t >> 6) * 2] = lsum;
        red[(t >> 6) * 2 + 1] = lss;
    }
    __syncthreads();
    const float tot = red[0] + red[2] + red[4] + red[6];
    const float tot2 = red[1] + red[3] + red[5] + red[7];
    const float mean = tot * (1.f / 1024.f);
    const float var = tot2 * (1.f / 1024.f) - mean * mean;
    const float rstd = rsqrtf(var + EPSV);
#pragma unroll
    for (int r = 0; r < 4; ++r) {
        const int i = t + 256 * r;
        const float y = (xs[r] - mean) * rstd * gw[i] + bw[i];
        out[b * 1024 + i] = f2bf(y);
    }
}

__global__ __launch_bounds__(256) void attn_ln(const unsigned short* __restrict__ qkv_c,
                                               const unsigned short* __restrict__ qkv_m,
                                               const float* __restrict__ g1,
                                               const float* __restrict__ be1,
                                               const float* __restrict__ g2,
                                               const float* __restrict__ be2,
                                               unsigned short* __restrict__ ln1,
                                               unsigned short* __restrict__ ln2) {
    __shared__ float qc[48 * 65];
    __shared__ float qm[48 * 65];
    __shared__ float sS[256];
    __shared__ float sP[256];
    __shared__ float red[8];
    const int t = threadIdx.x;
    const long b = blockIdx.x;

    const unsigned short* rc = qkv_c + b * QKV3;
    const unsigned short* rm = qkv_m + b * QKV3;
#pragma unroll
    for (int it = 0; it < 3; ++it) {
        const int i0 = t * 4 + it * 1024;
        ushort4 vc = *(const ushort4*)(rc + i0);
        ushort4 vm = *(const ushort4*)(rm + i0);
        const int o = i0 + (i0 >> 6);
        qc[o + 0] = bf2f(vc.x); qc[o + 1] = bf2f(vc.y);
        qc[o + 2] = bf2f(vc.z); qc[o + 3] = bf2f(vc.w);
        qm[o + 0] = bf2f(vm.x); qm[o + 1] = bf2f(vm.y);
        qm[o + 2] = bf2f(vm.z); qm[o + 3] = bf2f(vm.w);
    }
    __syncthreads();
    attn_path(qc, qm + 16 * 65, qm + 32 * 65, g1, be1, ln1, b, sS, sP, red, t);
    __syncthreads();
    attn_path(qm, qc + 16 * 65, qc + 32 * 65, g2, be2, ln2, b, sS, sP, red, t);
}

// -------------------------------- launch ---------------------------------------
extern "C" void kernel_launch(void* const* d_in, const int* in_sizes, int n_in,
                              void* d_out, int out_size, void* d_ws, size_t ws_size,
                              hipStream_t stream) {
    const float* cnn    = (const float*)d_in[0];
    const float* mlp    = (const float*)d_in[1];
    const float* W_cqkv = (const float*)d_in[2];
    const float* b_cqkv = (const float*)d_in[3];
    const float* W_mqkv = (const float*)d_in[4];
    const float* b_mqkv = (const float*)d_in[5];
    const float* g1     = (const float*)d_in[6];
    const float* be1    = (const float*)d_in[7];
    const float* g2     = (const float*)d_in[8];
    const float* be2    = (const float*)d_in[9];
    const float* W_cproj = (const float*)d_in[10];
    const float* b_cproj = (const float*)d_in[11];
    const float* W_mproj = (const float*)d_in[12];
    const float* b_mproj = (const float*)d_in[13];
    float* out = (float*)d_out;
    char* ws = (char*)d_ws;

    unsigned short* Abf_c = (unsigned short*)(ws + 0);           // 33,554,432 B
    unsigned short* Abf_m = (unsigned short*)(ws + 33554432);    // 33,554,432 B
    unsigned short* WqT_c = (unsigned short*)(ws + 67108864);    // 12,582,912 B
    unsigned short* WqT_m = (unsigned short*)(ws + 79691776);    // 12,582,912 B
    unsigned short* qkv_c = (unsigned short*)(ws + 92274688);    // 50,331,648 B
    unsigned short* qkv_m = (unsigned short*)(ws + 142606336);   // 50,331,648 B
    unsigned short* ln1   = (unsigned short*)(ws + 0);           // alias Abf_c
    unsigned short* ln2   = (unsigned short*)(ws + 16777216);    // alias Abf_c
    unsigned short* WpT_c = (unsigned short*)(ws + 33554432);    // alias Abf_m
    unsigned short* WpT_m = (unsigned short*)(ws + 37748736);    // alias Abf_m

    dim3 tb(32, 8);

    cvt2_f32_bf16<<<16384, 256, 0, stream>>>(cnn, Abf_c, mlp, Abf_m, (long)NROWS * DIM);
    cvt_transpose<<<dim3(QKV3 / 32, DIM / 32), tb, 0, stream>>>(W_cqkv, WqT_c, DIM, QKV3);
    cvt_transpose<<<dim3(QKV3 / 32, DIM / 32), tb, 0, stream>>>(W_mqkv, WqT_m, DIM, QKV3);

    // fused QKV GEMM pair: (8192x2048)*(2048x3072) x2, grid 768 (= 96 per XCD)
    gemm256<0><<<768, 512, 0, stream>>>(Abf_c, WqT_c, b_cqkv, nullptr, qkv_c,
                                        Abf_m, WqT_m, b_mqkv, nullptr, qkv_m,
                                        NROWS, QKV3, DIM, QKV3 / 256);

    attn_ln<<<NROWS, 256, 0, stream>>>(qkv_c, qkv_m, g1, be1, g2, be2, ln1, ln2);

    cvt_transpose<<<dim3(DIM / 32, HIDN / 32), tb, 0, stream>>>(W_cproj, WpT_c, HIDN, DIM);
    cvt_transpose<<<dim3(DIM / 32, HIDN / 32), tb, 0, stream>>>(W_mproj, WpT_m, HIDN, DIM);

    // fused proj GEMM pair: (8192x1024)*(1024x2048) x2 + bias + residual -> f32
    gemm256<1><<<512, 512, 0, stream>>>(ln1, WpT_c, b_cproj, cnn, out,
                                        ln2, WpT_m, b_mproj, mlp, out + (size_t)NROWS * DIM,
                                        NROWS, DIM, HIDN, DIM / 256);
}